// Round 1
// baseline (1941.447 us; speedup 1.0000x reference)
//
#include <hip/hip_runtime.h>

// ---------------------------------------------------------------------------
// SparseVoxelNet: sparse U-Net forward.
//   e1 = BNReLU(sconv27(feats, nbr0, W1))   [N0,32]
//   e2 = BNReLU(sconv27(e1,    nbr1, W2))   [N1,64]
//   e3 = BNReLU(sconv27(e2,    nbr2, W3))   [N2,128]
//   d2 = BNReLU(upconv(e3, up1, W4))        [N1,64]
//   d1 = BNReLU(upconv(d2, up0, W5))        [N0,32]
//   out = d1 @ Wout                         [N0,2]
// Round 1: correctness-first fp32, one thread per (row, cout).
// ---------------------------------------------------------------------------

template<int CIN, int COUT>
__global__ void sconv_kernel(const float* __restrict__ in, const int* __restrict__ nbr,
                             const float* __restrict__ W, float* __restrict__ out, int N) {
    long long gid = (long long)blockIdx.x * blockDim.x + threadIdx.x;
    long long total = (long long)N * COUT;
    if (gid >= total) return;
    int row = (int)(gid / COUT);
    int co  = (int)(gid % COUT);
    float acc = 0.0f;
    for (int k = 0; k < 27; ++k) {
        int idx = nbr[(long long)k * N + row];
        if (idx >= 0) {
            const float* ip = in + (long long)idx * CIN;
            const float* wp = W + ((long long)k * CIN) * COUT + co;
            #pragma unroll
            for (int ci = 0; ci < CIN; ++ci)
                acc = fmaf(ip[ci], wp[ci * COUT], acc);
        }
    }
    out[(long long)row * COUT + co] = acc;
}

template<int CIN, int COUT>
__global__ void upconv_kernel(const float* __restrict__ in, const int* __restrict__ pidx,
                              const int* __restrict__ poff, const float* __restrict__ W,
                              float* __restrict__ out, int N) {
    long long gid = (long long)blockIdx.x * blockDim.x + threadIdx.x;
    long long total = (long long)N * COUT;
    if (gid >= total) return;
    int row = (int)(gid / COUT);
    int co  = (int)(gid % COUT);
    int p   = pidx[row];
    int off = poff[row];
    float acc = 0.0f;
    if (p >= 0) {
        const float* ip = in + (long long)p * CIN;
        const float* wp = W + ((long long)off * CIN) * COUT + co;
        #pragma unroll
        for (int ci = 0; ci < CIN; ++ci)
            acc = fmaf(ip[ci], wp[ci * COUT], acc);
    }
    out[(long long)row * COUT + co] = acc;
}

// Per-channel sum & sumsq over rows. stats[0..C)=sum, stats[C..2C)=sumsq (pre-zeroed).
template<int C>
__global__ void stats_kernel(const float* __restrict__ x, float* __restrict__ stats, int N) {
    constexpr int RPB = 256 / C;         // rows covered per block-iteration
    int c  = threadIdx.x % C;
    int r0 = threadIdx.x / C;
    float s = 0.0f, ss = 0.0f;
    for (long long row = (long long)blockIdx.x * RPB + r0; row < N;
         row += (long long)gridDim.x * RPB) {
        float v = x[row * C + c];
        s += v;
        ss += v * v;
    }
    __shared__ float ls[256], lss[256];
    ls[threadIdx.x] = s; lss[threadIdx.x] = ss;
    __syncthreads();
    for (int str = 128; str >= C; str >>= 1) {
        if (threadIdx.x < str) {
            ls[threadIdx.x]  += ls[threadIdx.x + str];
            lss[threadIdx.x] += lss[threadIdx.x + str];
        }
        __syncthreads();
    }
    if (threadIdx.x < C) {
        atomicAdd(&stats[c],     ls[threadIdx.x]);
        atomicAdd(&stats[C + c], lss[threadIdx.x]);
    }
}

template<int C>
__global__ void bnrelu_kernel(float* __restrict__ x, const float* __restrict__ stats,
                              const float* __restrict__ g, const float* __restrict__ b, int N) {
    long long i = (long long)blockIdx.x * blockDim.x + threadIdx.x;
    long long total = (long long)N * C;
    if (i >= total) return;
    int c = (int)(i % C);
    float inv_n = 1.0f / (float)N;
    float mu  = stats[c] * inv_n;
    float var = stats[C + c] * inv_n - mu * mu;
    float v = (x[i] - mu) * rsqrtf(var + 1e-5f) * g[c] + b[c];
    x[i] = v > 0.0f ? v : 0.0f;
}

__global__ void final_kernel(const float* __restrict__ d1, const float* __restrict__ Wout,
                             float* __restrict__ out, int N) {
    int i = blockIdx.x * blockDim.x + threadIdx.x;
    if (i >= N) return;
    const float* ip = d1 + (long long)i * 32;
    float a0 = 0.0f, a1 = 0.0f;
    #pragma unroll
    for (int c = 0; c < 32; ++c) {
        a0 = fmaf(ip[c], Wout[c * 2 + 0], a0);
        a1 = fmaf(ip[c], Wout[c * 2 + 1], a1);
    }
    out[(long long)i * 2 + 0] = a0;
    out[(long long)i * 2 + 1] = a1;
}

extern "C" void kernel_launch(void* const* d_in, const int* in_sizes, int n_in,
                              void* d_out, int out_size, void* d_ws, size_t ws_size,
                              hipStream_t stream) {
    const float* feats = (const float*)d_in[0];
    const float* W1    = (const float*)d_in[1];
    const float* W2    = (const float*)d_in[2];
    const float* W3    = (const float*)d_in[3];
    const float* W4    = (const float*)d_in[4];
    const float* W5    = (const float*)d_in[5];
    const float* Wout  = (const float*)d_in[6];
    const float* g1 = (const float*)d_in[7],  *b1 = (const float*)d_in[8];
    const float* g2 = (const float*)d_in[9],  *b2 = (const float*)d_in[10];
    const float* g3 = (const float*)d_in[11], *b3 = (const float*)d_in[12];
    const float* g4 = (const float*)d_in[13], *b4 = (const float*)d_in[14];
    const float* g5 = (const float*)d_in[15], *b5 = (const float*)d_in[16];
    const int* nbr0 = (const int*)d_in[17];
    const int* nbr1 = (const int*)d_in[18];
    const int* nbr2 = (const int*)d_in[19];
    const int* up1_idx = (const int*)d_in[20];
    const int* up1_off = (const int*)d_in[21];
    const int* up0_idx = (const int*)d_in[22];
    const int* up0_off = (const int*)d_in[23];

    const int N0 = in_sizes[0] / 2;
    const int N1 = in_sizes[20];
    const int N2 = in_sizes[19] / 27;

    // Workspace layout (floats):
    //   [0, 1024)          : BN stats (5 layers, 2*C each; zeroed every call)
    //   bufA: N0*32        : z1/e1, later z5/d1
    //   bufB: N1*64        : z2/e2
    //   bufC: N2*128       : z3/e3
    //   bufD: N1*64        : z4/d2
    float* ws = (float*)d_ws;
    float* st1 = ws;            // 2*32
    float* st2 = ws + 64;       // 2*64
    float* st3 = ws + 192;      // 2*128
    float* st4 = ws + 448;      // 2*64
    float* st5 = ws + 576;      // 2*32
    float* bufA = ws + 1024;
    float* bufB = bufA + (long long)N0 * 32;
    float* bufC = bufB + (long long)N1 * 64;
    float* bufD = bufC + (long long)N2 * 128;

    hipMemsetAsync(ws, 0, 1024 * sizeof(float), stream);

    const int BS = 256;
    const int RED_BLOCKS = 1024;
    auto blocks = [](long long total, int bs) { return (int)((total + bs - 1) / bs); };

    // ---- enc1: conv(2->32, nbr0) + BN + ReLU
    sconv_kernel<2, 32><<<blocks((long long)N0 * 32, BS), BS, 0, stream>>>(feats, nbr0, W1, bufA, N0);
    stats_kernel<32><<<RED_BLOCKS, 256, 0, stream>>>(bufA, st1, N0);
    bnrelu_kernel<32><<<blocks((long long)N0 * 32, BS), BS, 0, stream>>>(bufA, st1, g1, b1, N0);

    // ---- enc2: conv(32->64, nbr1) + BN + ReLU
    sconv_kernel<32, 64><<<blocks((long long)N1 * 64, BS), BS, 0, stream>>>(bufA, nbr1, W2, bufB, N1);
    stats_kernel<64><<<RED_BLOCKS, 256, 0, stream>>>(bufB, st2, N1);
    bnrelu_kernel<64><<<blocks((long long)N1 * 64, BS), BS, 0, stream>>>(bufB, st2, g2, b2, N1);

    // ---- enc3: conv(64->128, nbr2) + BN + ReLU
    sconv_kernel<64, 128><<<blocks((long long)N2 * 128, BS), BS, 0, stream>>>(bufB, nbr2, W3, bufC, N2);
    stats_kernel<128><<<RED_BLOCKS, 256, 0, stream>>>(bufC, st3, N2);
    bnrelu_kernel<128><<<blocks((long long)N2 * 128, BS), BS, 0, stream>>>(bufC, st3, g3, b3, N2);

    // ---- dec2: upconv(128->64) + BN + ReLU
    upconv_kernel<128, 64><<<blocks((long long)N1 * 64, BS), BS, 0, stream>>>(bufC, up1_idx, up1_off, W4, bufD, N1);
    stats_kernel<64><<<RED_BLOCKS, 256, 0, stream>>>(bufD, st4, N1);
    bnrelu_kernel<64><<<blocks((long long)N1 * 64, BS), BS, 0, stream>>>(bufD, st4, g4, b4, N1);

    // ---- dec1: upconv(64->32) + BN + ReLU  (bufA reusable: e1 dead after enc2)
    upconv_kernel<64, 32><<<blocks((long long)N0 * 32, BS), BS, 0, stream>>>(bufD, up0_idx, up0_off, W5, bufA, N0);
    stats_kernel<32><<<RED_BLOCKS, 256, 0, stream>>>(bufA, st5, N0);
    bnrelu_kernel<32><<<blocks((long long)N0 * 32, BS), BS, 0, stream>>>(bufA, st5, g5, b5, N0);

    // ---- out: d1 @ Wout
    final_kernel<<<blocks(N0, BS), BS, 0, stream>>>(bufA, Wout, (float*)d_out, N0);
}

// Round 2
// 1148.354 us; speedup vs baseline: 1.6906x; 1.6906x over previous
//
#include <hip/hip_runtime.h>
#include <hip/hip_bf16.h>

typedef __attribute__((ext_vector_type(4))) float  f32x4;
typedef __attribute__((ext_vector_type(8))) short  short8;   // 8 x bf16 bits
typedef __attribute__((ext_vector_type(4))) short  short4v;

__device__ __forceinline__ void gload_lds16(const void* g, void* l) {
    __builtin_amdgcn_global_load_lds(
        (const __attribute__((address_space(1))) unsigned*)(g),
        (__attribute__((address_space(3))) unsigned*)(l),
        16, 0, 0);
}

__device__ __forceinline__ short f2bf(float f) {
    __hip_bfloat16 h = __float2bfloat16(f);
    short s; __builtin_memcpy(&s, &h, 2);
    return s;
}

// ---------------------------------------------------------------------------
// conv1: 2->32, thread per row, W1 cached in LDS.
// ---------------------------------------------------------------------------
__global__ void conv1_kernel(const float* __restrict__ feats, const int* __restrict__ nbr,
                             const float* __restrict__ W1, float* __restrict__ out, int N) {
    __shared__ float w[27 * 64];
    for (int i = threadIdx.x; i < 27 * 64; i += 256) w[i] = W1[i];
    __syncthreads();
    long long row = (long long)blockIdx.x * blockDim.x + threadIdx.x;
    if (row >= N) return;
    float acc[32];
    #pragma unroll
    for (int c = 0; c < 32; ++c) acc[c] = 0.0f;
    for (int k = 0; k < 27; ++k) {
        int idx = nbr[(long long)k * N + row];
        if (idx >= 0) {
            float f0 = feats[(long long)idx * 2];
            float f1 = feats[(long long)idx * 2 + 1];
            const float* wk = w + k * 64;
            #pragma unroll
            for (int c = 0; c < 32; ++c)
                acc[c] = fmaf(f0, wk[c], fmaf(f1, wk[32 + c], acc[c]));
        }
    }
    float* op = out + row * 32;
    #pragma unroll
    for (int c = 0; c < 32; c += 4)
        *(f32x4*)(op + c) = (f32x4){acc[c], acc[c+1], acc[c+2], acc[c+3]};
}

// ---------------------------------------------------------------------------
// Weight convert+transpose: W[k][ci][co] fp32  ->  Wt[k][co][ci] bf16
// ---------------------------------------------------------------------------
__global__ void wt_kernel(const float* __restrict__ W, short* __restrict__ Wt,
                          int NK, int CIN, int COUT) {
    int gid = blockIdx.x * 256 + threadIdx.x;
    int total = NK * CIN * COUT;
    if (gid >= total) return;
    int k = gid / (CIN * COUT), rem = gid % (CIN * COUT);
    int ci = rem / COUT, co = rem % COUT;
    Wt[((long long)k * COUT + co) * CIN + ci] = f2bf(W[gid]);
}

// ---------------------------------------------------------------------------
// MFMA implicit-GEMM conv. Block = 256 thr = 4 waves, tile M=64 x COUT.
// A-tile gathered into LDS (XOR-swizzled via pre-swizzled global source),
// B fragments loaded straight from transposed bf16 weights (16B contiguous).
// UP variant: virtual neighbor list idx = (poff[r]==k ? pidx[r] : -1).
// ---------------------------------------------------------------------------
template<int CIN, int COUT, int NK, bool UP>
__launch_bounds__(256)
__global__ void mconv_kernel(const short* __restrict__ inb, const int* __restrict__ nbr,
                             const int* __restrict__ poff, const short* __restrict__ Wt,
                             const short* __restrict__ zrow, float* __restrict__ out, int N) {
    constexpr int SPR = CIN / 8;            // 16B segments per row
    constexpr int NTILE = COUT / 16;
    constexpr int KC = CIN / 32;
    constexpr int IT = (64 * SPR) / 256;    // staging iters per thread
    __shared__ __align__(16) short As[64 * CIN];

    int tid = threadIdx.x, lane = tid & 63, wave = tid >> 6;
    int rbase = blockIdx.x * 64;

    f32x4 acc[NTILE];
    #pragma unroll
    for (int c = 0; c < NTILE; ++c) acc[c] = (f32x4){0.f, 0.f, 0.f, 0.f};

    for (int k = 0; k < NK; ++k) {
        // ---- stage A tile (64 rows x CIN bf16), swizzled source, linear dest
        #pragma unroll
        for (int it = 0; it < IT; ++it) {
            int p = it * 256 + tid;
            int row = p / SPR, sp = p % SPR;
            int slog = sp ^ (row & (SPR - 1));
            int rg = rbase + row; if (rg >= N) rg = N - 1;
            int idx;
            if (UP) {
                idx = (poff[rg] == k) ? nbr[rg] : -1;
            } else {
                idx = nbr[(long long)k * N + rg];
            }
            const short* src = (idx >= 0) ? (inb + (long long)idx * CIN + slog * 8)
                                          : (zrow + slog * 8);
            gload_lds16(src, &As[p * 8]);
        }
        __syncthreads();
        // ---- MFMA over K = NK*CIN
        #pragma unroll
        for (int kc = 0; kc < KC; ++kc) {
            int r = wave * 16 + (lane & 15);
            int slog = kc * 4 + (lane >> 4);
            int sp = slog ^ (r & (SPR - 1));
            short8 a = *(const short8*)&As[(r * SPR + sp) * 8];
            #pragma unroll
            for (int c = 0; c < NTILE; ++c) {
                int col = c * 16 + (lane & 15);
                short8 b = *(const short8*)(Wt + ((long long)k * COUT + col) * CIN
                                            + kc * 32 + 8 * (lane >> 4));
                acc[c] = __builtin_amdgcn_mfma_f32_16x16x32_bf16(a, b, acc[c], 0, 0, 0);
            }
        }
        __syncthreads();
    }
    // ---- epilogue: C/D layout col=lane&15, row=4*(lane>>4)+j
    int r0 = rbase + wave * 16 + (lane >> 4) * 4;
    #pragma unroll
    for (int c = 0; c < NTILE; ++c) {
        int col = c * 16 + (lane & 15);
        #pragma unroll
        for (int j = 0; j < 4; ++j) {
            int r = r0 + j;
            if (r < N) out[(long long)r * COUT + col] = acc[c][j];
        }
    }
}

// ---------------------------------------------------------------------------
// Per-channel sum & sumsq (vectorized f32x4). stats pre-zeroed.
// ---------------------------------------------------------------------------
template<int C>
__global__ void stats_kernel(const float* __restrict__ x, float* __restrict__ stats, int N) {
    constexpr int LPR = C / 4;              // threads per row
    constexpr int RPB = 256 / LPR;
    int cl = threadIdx.x % LPR;
    int r0 = threadIdx.x / LPR;
    f32x4 s = (f32x4){0.f,0.f,0.f,0.f}, ss = (f32x4){0.f,0.f,0.f,0.f};
    for (long long row = (long long)blockIdx.x * RPB + r0; row < N;
         row += (long long)gridDim.x * RPB) {
        f32x4 v = *(const f32x4*)(x + row * C + cl * 4);
        s += v; ss += v * v;
    }
    __shared__ f32x4 ls[256], lss[256];
    ls[threadIdx.x] = s; lss[threadIdx.x] = ss;
    __syncthreads();
    for (int str = 128; str >= LPR; str >>= 1) {
        if (threadIdx.x < str) {
            ls[threadIdx.x]  += ls[threadIdx.x + str];
            lss[threadIdx.x] += lss[threadIdx.x + str];
        }
        __syncthreads();
    }
    if (threadIdx.x < LPR) {
        f32x4 a = ls[threadIdx.x], q = lss[threadIdx.x];
        #pragma unroll
        for (int j = 0; j < 4; ++j) {
            atomicAdd(&stats[cl * 4 + j],     a[j]);
            atomicAdd(&stats[C + cl * 4 + j], q[j]);
        }
    }
}

// ---------------------------------------------------------------------------
// BN + ReLU; writes bf16 (for next conv) or fp32 (last hidden layer).
// ---------------------------------------------------------------------------
template<int C, bool BF16OUT>
__global__ void bnrelu_kernel(const float* __restrict__ x, const float* __restrict__ stats,
                              const float* __restrict__ g, const float* __restrict__ b,
                              void* outp, int N) {
    long long i = (long long)blockIdx.x * blockDim.x + threadIdx.x;  // group of 4
    long long total = (long long)N * C / 4;
    if (i >= total) return;
    int c0 = (int)((i * 4) % C);
    f32x4 v = *(const f32x4*)(x + i * 4);
    float inv_n = 1.0f / (float)N;
    float y[4];
    #pragma unroll
    for (int j = 0; j < 4; ++j) {
        int c = c0 + j;
        float mu  = stats[c] * inv_n;
        float var = stats[C + c] * inv_n - mu * mu;
        float t = (v[j] - mu) * rsqrtf(var + 1e-5f) * g[c] + b[c];
        y[j] = t > 0.0f ? t : 0.0f;
    }
    if (BF16OUT) {
        short4v o = (short4v){f2bf(y[0]), f2bf(y[1]), f2bf(y[2]), f2bf(y[3])};
        *(short4v*)((short*)outp + i * 4) = o;
    } else {
        *(f32x4*)((float*)outp + i * 4) = (f32x4){y[0], y[1], y[2], y[3]};
    }
}

__global__ void final_kernel(const float* __restrict__ d1, const float* __restrict__ Wout,
                             float* __restrict__ out, int N) {
    int i = blockIdx.x * blockDim.x + threadIdx.x;
    if (i >= N) return;
    const float* ip = d1 + (long long)i * 32;
    float a0 = 0.0f, a1 = 0.0f;
    #pragma unroll
    for (int c = 0; c < 32; ++c) {
        a0 = fmaf(ip[c], Wout[c * 2 + 0], a0);
        a1 = fmaf(ip[c], Wout[c * 2 + 1], a1);
    }
    out[(long long)i * 2 + 0] = a0;
    out[(long long)i * 2 + 1] = a1;
}

extern "C" void kernel_launch(void* const* d_in, const int* in_sizes, int n_in,
                              void* d_out, int out_size, void* d_ws, size_t ws_size,
                              hipStream_t stream) {
    const float* feats = (const float*)d_in[0];
    const float* W1   = (const float*)d_in[1];
    const float* W2   = (const float*)d_in[2];
    const float* W3   = (const float*)d_in[3];
    const float* W4   = (const float*)d_in[4];
    const float* W5   = (const float*)d_in[5];
    const float* Wout = (const float*)d_in[6];
    const float* g1 = (const float*)d_in[7],  *b1 = (const float*)d_in[8];
    const float* g2 = (const float*)d_in[9],  *b2 = (const float*)d_in[10];
    const float* g3 = (const float*)d_in[11], *b3 = (const float*)d_in[12];
    const float* g4 = (const float*)d_in[13], *b4 = (const float*)d_in[14];
    const float* g5 = (const float*)d_in[15], *b5 = (const float*)d_in[16];
    const int* nbr0 = (const int*)d_in[17];
    const int* nbr1 = (const int*)d_in[18];
    const int* nbr2 = (const int*)d_in[19];
    const int* up1_idx = (const int*)d_in[20];
    const int* up1_off = (const int*)d_in[21];
    const int* up0_idx = (const int*)d_in[22];
    const int* up0_off = (const int*)d_in[23];

    const int N0 = in_sizes[0] / 2;
    const int N1 = in_sizes[20];
    const int N2 = in_sizes[19] / 27;

    // ---- workspace carve-out (256B aligned chunks)
    char* cur = (char*)d_ws;
    auto alloc = [&](size_t bytes) { char* p = cur; cur += (bytes + 255) & ~255ULL; return p; };
    float* stats = (float*)alloc(4096);          // 5 layers' stats + zero row
    float* st1 = stats;         // 2*32
    float* st2 = stats + 64;    // 2*64
    float* st3 = stats + 192;   // 2*128
    float* st4 = stats + 448;   // 2*64
    float* st5 = stats + 576;   // 2*32
    short* zrow = (short*)((char*)stats + 2560); // 256 bf16 zeros (covers CIN<=128)

    size_t zmax = (size_t)N0 * 32;
    if ((size_t)N1 * 64  > zmax) zmax = (size_t)N1 * 64;
    if ((size_t)N2 * 128 > zmax) zmax = (size_t)N2 * 128;
    float* zbuf = (float*)alloc(zmax * 4);       // fp32 conv output (per-layer reuse)
    short* e1b  = (short*)alloc((size_t)N0 * 32 * 2);
    short* e2b  = (short*)alloc((size_t)N1 * 64 * 2);
    short* e3b  = (short*)alloc((size_t)N2 * 128 * 2);
    short* d2b  = (short*)alloc((size_t)N1 * 64 * 2);
    float* d1f  = (float*)alloc((size_t)N0 * 32 * 4);
    short* W2t  = (short*)alloc((size_t)27 * 32 * 64 * 2);
    short* W3t  = (short*)alloc((size_t)27 * 64 * 128 * 2);
    short* W4t  = (short*)alloc((size_t)8 * 128 * 64 * 2);
    short* W5t  = (short*)alloc((size_t)8 * 64 * 32 * 2);

    hipMemsetAsync(stats, 0, 4096, stream);

    auto cdiv = [](long long a, long long b) { return (int)((a + b - 1) / b); };

    // weight transposes (tiny)
    wt_kernel<<<cdiv(27 * 32 * 64, 256), 256, 0, stream>>>(W2, W2t, 27, 32, 64);
    wt_kernel<<<cdiv(27 * 64 * 128, 256), 256, 0, stream>>>(W3, W3t, 27, 64, 128);
    wt_kernel<<<cdiv(8 * 128 * 64, 256), 256, 0, stream>>>(W4, W4t, 8, 128, 64);
    wt_kernel<<<cdiv(8 * 64 * 32, 256), 256, 0, stream>>>(W5, W5t, 8, 64, 32);

    // ---- enc1: conv(2->32) fp32 + BN + ReLU -> bf16
    conv1_kernel<<<cdiv(N0, 256), 256, 0, stream>>>(feats, nbr0, W1, zbuf, N0);
    stats_kernel<32><<<1024, 256, 0, stream>>>(zbuf, st1, N0);
    bnrelu_kernel<32, true><<<cdiv((long long)N0 * 8, 256), 256, 0, stream>>>(zbuf, st1, g1, b1, e1b, N0);

    // ---- enc2: mfma conv(32->64, nbr1)
    mconv_kernel<32, 64, 27, false><<<cdiv(N1, 64), 256, 0, stream>>>(e1b, nbr1, nullptr, W2t, zrow, zbuf, N1);
    stats_kernel<64><<<1024, 256, 0, stream>>>(zbuf, st2, N1);
    bnrelu_kernel<64, true><<<cdiv((long long)N1 * 16, 256), 256, 0, stream>>>(zbuf, st2, g2, b2, e2b, N1);

    // ---- enc3: mfma conv(64->128, nbr2)
    mconv_kernel<64, 128, 27, false><<<cdiv(N2, 64), 256, 0, stream>>>(e2b, nbr2, nullptr, W3t, zrow, zbuf, N2);
    stats_kernel<128><<<1024, 256, 0, stream>>>(zbuf, st3, N2);
    bnrelu_kernel<128, true><<<cdiv((long long)N2 * 32, 256), 256, 0, stream>>>(zbuf, st3, g3, b3, e3b, N2);

    // ---- dec2: mfma upconv(128->64)
    mconv_kernel<128, 64, 8, true><<<cdiv(N1, 64), 256, 0, stream>>>(e3b, up1_idx, up1_off, W4t, zrow, zbuf, N1);
    stats_kernel<64><<<1024, 256, 0, stream>>>(zbuf, st4, N1);
    bnrelu_kernel<64, true><<<cdiv((long long)N1 * 16, 256), 256, 0, stream>>>(zbuf, st4, g4, b4, d2b, N1);

    // ---- dec1: mfma upconv(64->32), d1 kept fp32
    mconv_kernel<64, 32, 8, true><<<cdiv(N0, 64), 256, 0, stream>>>(d2b, up0_idx, up0_off, W5t, zrow, zbuf, N0);
    stats_kernel<32><<<1024, 256, 0, stream>>>(zbuf, st5, N0);
    bnrelu_kernel<32, false><<<cdiv((long long)N0 * 8, 256), 256, 0, stream>>>(zbuf, st5, g5, b5, d1f, N0);

    // ---- out: d1 @ Wout
    final_kernel<<<cdiv(N0, 256), 256, 0, stream>>>(d1f, Wout, (float*)d_out, N0);
}

// Round 3
// 500.039 us; speedup vs baseline: 3.8826x; 2.2965x over previous
//
#include <hip/hip_runtime.h>
#include <hip/hip_bf16.h>

typedef __attribute__((ext_vector_type(4))) float  f32x4;
typedef __attribute__((ext_vector_type(8))) short  short8;
typedef __attribute__((ext_vector_type(2))) float  flt2;
typedef long long ll;

__device__ __forceinline__ short f2bf(float f) {
    __hip_bfloat16 h = __float2bfloat16(f);
    short s; __builtin_memcpy(&s, &h, 2);
    return s;
}
__device__ __forceinline__ float bf2f(short s) {
    unsigned u = ((unsigned)(unsigned short)s) << 16;
    float f; __builtin_memcpy(&f, &u, 4);
    return f;
}

// ---------------------------------------------------------------------------
// prep: convert/transpose all weights to bf16 [k][co][ci] (W1: [co][64] padded)
// ---------------------------------------------------------------------------
__global__ void prep_kernel(const float* __restrict__ W1, const float* __restrict__ W2,
                            const float* __restrict__ W3, const float* __restrict__ W4,
                            const float* __restrict__ W5,
                            short* W1t, short* W2t, short* W3t, short* W4t, short* W5t) {
    int gid = blockIdx.x * 256 + threadIdx.x;
    if (gid < 32 * 64) {                       // W1t[co][e], e=2k+ci, pad e>=54
        int co = gid >> 6, e = gid & 63;
        float v = 0.f;
        if (e < 54) { int k = e >> 1, ci = e & 1; v = W1[(k * 2 + ci) * 32 + co]; }
        W1t[gid] = f2bf(v);
        return;
    }
    int g = gid - 32 * 64;
    if (g < 27 * 64 * 32) { int k = g / (64*32), r = g % (64*32), co = r >> 5, ci = r & 31;
        W2t[g] = f2bf(W2[((ll)k * 32 + ci) * 64 + co]); return; }
    g -= 27 * 64 * 32;
    if (g < 27 * 128 * 64) { int k = g / (128*64), r = g % (128*64), co = r >> 6, ci = r & 63;
        W3t[g] = f2bf(W3[((ll)k * 64 + ci) * 128 + co]); return; }
    g -= 27 * 128 * 64;
    if (g < 8 * 64 * 128) { int k = g / (64*128), r = g % (64*128), co = r >> 7, ci = r & 127;
        W4t[g] = f2bf(W4[((ll)k * 128 + ci) * 64 + co]); return; }
    g -= 8 * 64 * 128;
    if (g < 8 * 32 * 64) { int k = g / (32*64), r = g % (32*64), co = r >> 6, ci = r & 63;
        W5t[g] = f2bf(W5[((ll)k * 64 + ci) * 32 + co]); return; }
}

// ---------------------------------------------------------------------------
// conv1 as dense MFMA GEMM: A[r][e] = feats[nbr[e/2][r]][e&1] (K=54 pad 64)
// ---------------------------------------------------------------------------
__launch_bounds__(256)
__global__ void c1_kernel(const float* __restrict__ feats, const int* __restrict__ nbr,
                          const short* __restrict__ W1t, short* __restrict__ out, int N) {
    int tid = threadIdx.x, lane = tid & 63, wave = tid >> 6;
    int rb = blockIdx.x * 64 + wave * 16;
    int r = rb + (lane & 15);
    int rl = r < N ? r : N - 1;
    int seg = lane >> 4;
    f32x4 acc[2];
    acc[0] = (f32x4){0,0,0,0}; acc[1] = (f32x4){0,0,0,0};
    short8 a[2];
    #pragma unroll
    for (int kc = 0; kc < 2; ++kc) {
        #pragma unroll
        for (int j = 0; j < 4; ++j) {
            int k = kc * 16 + seg * 4 + j;
            flt2 f = (flt2){0.f, 0.f};
            if (k < 27) {
                int idx = nbr[(ll)k * N + rl];
                if (idx >= 0) f = *(const flt2*)(feats + 2 * (ll)idx);
            }
            a[kc][2*j]   = f2bf(f[0]);
            a[kc][2*j+1] = f2bf(f[1]);
        }
    }
    #pragma unroll
    for (int kc = 0; kc < 2; ++kc)
        #pragma unroll
        for (int c = 0; c < 2; ++c) {
            short8 b = *(const short8*)(W1t + (c*16 + (lane & 15)) * 64 + kc * 32 + seg * 8);
            acc[c] = __builtin_amdgcn_mfma_f32_16x16x32_bf16(a[kc], b, acc[c], 0, 0, 0);
        }
    int r0 = rb + seg * 4;
    #pragma unroll
    for (int c = 0; c < 2; ++c) {
        int col = c * 16 + (lane & 15);
        #pragma unroll
        for (int j = 0; j < 4; ++j)
            if (r0 + j < N) out[(ll)(r0 + j) * 32 + col] = f2bf(acc[c][j]);
    }
}

// ---------------------------------------------------------------------------
// MFMA implicit-GEMM conv, register-direct A gather, no LDS, no barriers.
// Rotating prefetch: idx 2 tiles ahead, A-frags 1 tile ahead.
// ---------------------------------------------------------------------------
template<int CIN, int COUT, int NK>
__launch_bounds__(256)
__global__ void mconv_kernel(const short* __restrict__ inb, const int* __restrict__ nbr,
                             const short* __restrict__ Wt, short* __restrict__ out, int N) {
    constexpr int KC = CIN / 32, NT = COUT / 16;
    int tid = threadIdx.x, lane = tid & 63, wave = tid >> 6;
    int rb = blockIdx.x * 64 + wave * 16;
    int r = rb + (lane & 15);
    int rl = r < N ? r : N - 1;
    int seg = lane >> 4;
    f32x4 acc[NT];
    #pragma unroll
    for (int c = 0; c < NT; ++c) acc[c] = (f32x4){0,0,0,0};

    auto ldidx = [&](int k) { return nbr[(ll)k * N + rl]; };
    auto ldA = [&](short8* a, int idx) {
        const short8* base = (const short8*)(inb + (ll)(idx < 0 ? 0 : idx) * CIN);
        #pragma unroll
        for (int kc = 0; kc < KC; ++kc) {
            short8 v = base[kc * 4 + seg];
            if (idx < 0) v = (short8){0,0,0,0,0,0,0,0};
            a[kc] = v;
        }
    };

    int idx2 = ldidx(0);
    int idx3 = (NK > 1) ? ldidx(1) : -1;
    short8 aC[KC];
    ldA(aC, idx2);
    idx2 = idx3;
    for (int k = 0; k < NK; ++k) {
        short8 aN[KC];
        if (k + 1 < NK) ldA(aN, idx2);
        idx3 = (k + 2 < NK) ? ldidx(k + 2) : -1;
        const short* wk = Wt + (ll)k * COUT * CIN;
        #pragma unroll
        for (int kc = 0; kc < KC; ++kc)
            #pragma unroll
            for (int c = 0; c < NT; ++c) {
                short8 b = *(const short8*)(wk + (c*16 + (lane & 15)) * CIN + kc * 32 + seg * 8);
                acc[c] = __builtin_amdgcn_mfma_f32_16x16x32_bf16(aC[kc], b, acc[c], 0, 0, 0);
            }
        #pragma unroll
        for (int kc = 0; kc < KC; ++kc) aC[kc] = aN[kc];
        idx2 = idx3;
    }
    int r0 = rb + seg * 4;
    #pragma unroll
    for (int c = 0; c < NT; ++c) {
        int col = c * 16 + (lane & 15);
        #pragma unroll
        for (int j = 0; j < 4; ++j)
            if (r0 + j < N) out[(ll)(r0 + j) * COUT + col] = f2bf(acc[c][j]);
    }
}

// ---------------------------------------------------------------------------
// Transposed conv: A loaded ONCE per row (parent), masked per offset k.
// ---------------------------------------------------------------------------
template<int CIN, int COUT>
__launch_bounds__(256)
__global__ void mup_kernel(const short* __restrict__ inb, const int* __restrict__ pidx,
                           const int* __restrict__ poff, const short* __restrict__ Wt,
                           short* __restrict__ out, int N) {
    constexpr int KC = CIN / 32, NT = COUT / 16;
    int tid = threadIdx.x, lane = tid & 63, wave = tid >> 6;
    int rb = blockIdx.x * 64 + wave * 16;
    int r = rb + (lane & 15);
    int rl = r < N ? r : N - 1;
    int seg = lane >> 4;
    int p = pidx[rl];
    int off = poff[rl];
    short8 a[KC];
    const short8* base = (const short8*)(inb + (ll)(p < 0 ? 0 : p) * CIN);
    #pragma unroll
    for (int kc = 0; kc < KC; ++kc) {
        short8 v = base[kc * 4 + seg];
        if (p < 0) v = (short8){0,0,0,0,0,0,0,0};
        a[kc] = v;
    }
    f32x4 acc[NT];
    #pragma unroll
    for (int c = 0; c < NT; ++c) acc[c] = (f32x4){0,0,0,0};
    #pragma unroll
    for (int k = 0; k < 8; ++k) {
        bool m = (off == k);
        if (!__any(m)) continue;
        short8 ak[KC];
        #pragma unroll
        for (int kc = 0; kc < KC; ++kc)
            ak[kc] = m ? a[kc] : (short8){0,0,0,0,0,0,0,0};
        const short* wk = Wt + (ll)k * COUT * CIN;
        #pragma unroll
        for (int kc = 0; kc < KC; ++kc)
            #pragma unroll
            for (int c = 0; c < NT; ++c) {
                short8 b = *(const short8*)(wk + (c*16 + (lane & 15)) * CIN + kc * 32 + seg * 8);
                acc[c] = __builtin_amdgcn_mfma_f32_16x16x32_bf16(ak[kc], b, acc[c], 0, 0, 0);
            }
    }
    int r0 = rb + seg * 4;
    #pragma unroll
    for (int c = 0; c < NT; ++c) {
        int col = c * 16 + (lane & 15);
        #pragma unroll
        for (int j = 0; j < 4; ++j)
            if (r0 + j < N) out[(ll)(r0 + j) * COUT + col] = f2bf(acc[c][j]);
    }
}

// ---------------------------------------------------------------------------
// BN stats: block partials (deterministic), 256 blocks x [2C]
// ---------------------------------------------------------------------------
template<int C>
__global__ void statsp_kernel(const short* __restrict__ x, float* __restrict__ part, int N) {
    constexpr int LPR = C / 8;
    constexpr int RPB = 256 / LPR;
    int cl = threadIdx.x % LPR, r0 = threadIdx.x / LPR;
    float s[8] = {0,0,0,0,0,0,0,0}, q[8] = {0,0,0,0,0,0,0,0};
    for (ll row = (ll)blockIdx.x * RPB + r0; row < N; row += (ll)gridDim.x * RPB) {
        short8 v = *(const short8*)(x + row * C + cl * 8);
        #pragma unroll
        for (int j = 0; j < 8; ++j) { float f = bf2f(v[j]); s[j] += f; q[j] += f * f; }
    }
    __shared__ float ls[256][8], lq[256][8];
    #pragma unroll
    for (int j = 0; j < 8; ++j) { ls[threadIdx.x][j] = s[j]; lq[threadIdx.x][j] = q[j]; }
    __syncthreads();
    for (int str = 128; str >= LPR; str >>= 1) {
        if (threadIdx.x < str) {
            #pragma unroll
            for (int j = 0; j < 8; ++j) {
                ls[threadIdx.x][j] += ls[threadIdx.x + str][j];
                lq[threadIdx.x][j] += lq[threadIdx.x + str][j];
            }
        }
        __syncthreads();
    }
    if (threadIdx.x < LPR) {
        #pragma unroll
        for (int j = 0; j < 8; ++j) {
            part[(ll)blockIdx.x * 2 * C + threadIdx.x * 8 + j]     = ls[threadIdx.x][j];
            part[(ll)blockIdx.x * 2 * C + C + threadIdx.x * 8 + j] = lq[threadIdx.x][j];
        }
    }
}

// reduce partials -> per-channel scale A, shift B.  grid = C blocks.
__global__ void red_kernel(const float* __restrict__ part, const float* __restrict__ g,
                           const float* __restrict__ bb, float* __restrict__ A,
                           float* __restrict__ B, int C, int N) {
    int c = blockIdx.x;
    __shared__ float ls[256], lq[256];
    ls[threadIdx.x] = part[(ll)threadIdx.x * 2 * C + c];
    lq[threadIdx.x] = part[(ll)threadIdx.x * 2 * C + C + c];
    __syncthreads();
    for (int str = 128; str >= 1; str >>= 1) {
        if (threadIdx.x < str) {
            ls[threadIdx.x] += ls[threadIdx.x + str];
            lq[threadIdx.x] += lq[threadIdx.x + str];
        }
        __syncthreads();
    }
    if (threadIdx.x == 0) {
        float inv = 1.0f / (float)N;
        float mu = ls[0] * inv, var = lq[0] * inv - mu * mu;
        float a = g[c] * rsqrtf(var + 1e-5f);
        A[c] = a; B[c] = bb[c] - mu * a;
    }
}

template<int C>
__global__ void bnrelu_kernel(const short* __restrict__ x, const float* __restrict__ A,
                              const float* __restrict__ B, short* __restrict__ out, ll total8) {
    ll i = (ll)blockIdx.x * 256 + threadIdx.x;
    if (i >= total8) return;
    int c0 = (int)((i * 8) % C);
    short8 v = ((const short8*)x)[i];
    short8 o;
    #pragma unroll
    for (int j = 0; j < 8; ++j) {
        int c = c0 + j;
        float y = fmaf(bf2f(v[j]), A[c], B[c]);
        o[j] = f2bf(y > 0.f ? y : 0.f);
    }
    ((short8*)out)[i] = o;
}

// fused BN+ReLU+1x1 out conv: thread per row
__global__ void outk_kernel(const short* __restrict__ z, const float* __restrict__ A,
                            const float* __restrict__ B, const float* __restrict__ Wout,
                            float* __restrict__ out, int N) {
    __shared__ float w[64], sa[32], sb[32];
    if (threadIdx.x < 64) w[threadIdx.x] = Wout[threadIdx.x];
    if (threadIdx.x < 32) { sa[threadIdx.x] = A[threadIdx.x]; sb[threadIdx.x] = B[threadIdx.x]; }
    __syncthreads();
    int r = blockIdx.x * 256 + threadIdx.x;
    if (r >= N) return;
    const short8* zp = (const short8*)(z + (ll)r * 32);
    float o0 = 0.f, o1 = 0.f;
    #pragma unroll
    for (int s = 0; s < 4; ++s) {
        short8 v = zp[s];
        #pragma unroll
        for (int j = 0; j < 8; ++j) {
            int c = s * 8 + j;
            float y = fmaf(bf2f(v[j]), sa[c], sb[c]);
            y = y > 0.f ? y : 0.f;
            o0 = fmaf(y, w[2*c], o0);
            o1 = fmaf(y, w[2*c+1], o1);
        }
    }
    out[(ll)r * 2]     = o0;
    out[(ll)r * 2 + 1] = o1;
}

extern "C" void kernel_launch(void* const* d_in, const int* in_sizes, int n_in,
                              void* d_out, int out_size, void* d_ws, size_t ws_size,
                              hipStream_t stream) {
    const float* feats = (const float*)d_in[0];
    const float* W1 = (const float*)d_in[1];
    const float* W2 = (const float*)d_in[2];
    const float* W3 = (const float*)d_in[3];
    const float* W4 = (const float*)d_in[4];
    const float* W5 = (const float*)d_in[5];
    const float* Wout = (const float*)d_in[6];
    const float* g1 = (const float*)d_in[7],  *b1 = (const float*)d_in[8];
    const float* g2 = (const float*)d_in[9],  *b2 = (const float*)d_in[10];
    const float* g3 = (const float*)d_in[11], *b3 = (const float*)d_in[12];
    const float* g4 = (const float*)d_in[13], *b4 = (const float*)d_in[14];
    const float* g5 = (const float*)d_in[15], *b5 = (const float*)d_in[16];
    const int* nbr0 = (const int*)d_in[17];
    const int* nbr1 = (const int*)d_in[18];
    const int* nbr2 = (const int*)d_in[19];
    const int* up1_idx = (const int*)d_in[20];
    const int* up1_off = (const int*)d_in[21];
    const int* up0_idx = (const int*)d_in[22];
    const int* up0_off = (const int*)d_in[23];

    const int N0 = in_sizes[0] / 2;
    const int N1 = in_sizes[20];
    const int N2 = in_sizes[19] / 27;

    char* cur = (char*)d_ws;
    auto alloc = [&](size_t bytes) { char* p = cur; cur += (bytes + 255) & ~255ULL; return p; };

    float* stats = (float*)alloc(640 * 4);
    float* A1 = stats,       *B1c = stats + 32;
    float* A2 = stats + 64,  *B2c = stats + 128;
    float* A3 = stats + 192, *B3c = stats + 320;
    float* A4 = stats + 448, *B4c = stats + 512;
    float* A5 = stats + 576, *B5c = stats + 608;
    float* part = (float*)alloc(256 * 256 * 4);

    size_t zmax = (size_t)N1 * 64;
    if ((size_t)N0 * 32  > zmax) zmax = (size_t)N0 * 32;
    if ((size_t)N2 * 128 > zmax) zmax = (size_t)N2 * 128;
    short* zb  = (short*)alloc(zmax * 2);             // raw conv out (bf16, reused)
    short* e1b = (short*)alloc((size_t)N0 * 32 * 2);
    short* e2b = (short*)alloc((size_t)N1 * 64 * 2);
    short* e3b = (short*)alloc((size_t)N2 * 128 * 2);
    short* d2b = (short*)alloc((size_t)N1 * 64 * 2);
    short* W1t = (short*)alloc(32 * 64 * 2);
    short* W2t = (short*)alloc((size_t)27 * 64 * 32 * 2);
    short* W3t = (short*)alloc((size_t)27 * 128 * 64 * 2);
    short* W4t = (short*)alloc((size_t)8 * 64 * 128 * 2);
    short* W5t = (short*)alloc((size_t)8 * 32 * 64 * 2);

    auto cdiv = [](ll a, ll b) { return (int)((a + b - 1) / b); };

    prep_kernel<<<cdiv(2048 + 55296 + 221184 + 65536 + 16384, 256), 256, 0, stream>>>(
        W1, W2, W3, W4, W5, W1t, W2t, W3t, W4t, W5t);

    // L1: conv(2->32)
    c1_kernel<<<cdiv(N0, 64), 256, 0, stream>>>(feats, nbr0, W1t, zb, N0);
    statsp_kernel<32><<<256, 256, 0, stream>>>(zb, part, N0);
    red_kernel<<<32, 256, 0, stream>>>(part, g1, b1, A1, B1c, 32, N0);
    bnrelu_kernel<32><<<cdiv((ll)N0 * 4, 256), 256, 0, stream>>>(zb, A1, B1c, e1b, (ll)N0 * 4);

    // L2: conv(32->64)
    mconv_kernel<32, 64, 27><<<cdiv(N1, 64), 256, 0, stream>>>(e1b, nbr1, W2t, zb, N1);
    statsp_kernel<64><<<256, 256, 0, stream>>>(zb, part, N1);
    red_kernel<<<64, 256, 0, stream>>>(part, g2, b2, A2, B2c, 64, N1);
    bnrelu_kernel<64><<<cdiv((ll)N1 * 8, 256), 256, 0, stream>>>(zb, A2, B2c, e2b, (ll)N1 * 8);

    // L3: conv(64->128)
    mconv_kernel<64, 128, 27><<<cdiv(N2, 64), 256, 0, stream>>>(e2b, nbr2, W3t, zb, N2);
    statsp_kernel<128><<<256, 256, 0, stream>>>(zb, part, N2);
    red_kernel<<<128, 256, 0, stream>>>(part, g3, b3, A3, B3c, 128, N2);
    bnrelu_kernel<128><<<cdiv((ll)N2 * 16, 256), 256, 0, stream>>>(zb, A3, B3c, e3b, (ll)N2 * 16);

    // L4: upconv(128->64)
    mup_kernel<128, 64><<<cdiv(N1, 64), 256, 0, stream>>>(e3b, up1_idx, up1_off, W4t, zb, N1);
    statsp_kernel<64><<<256, 256, 0, stream>>>(zb, part, N1);
    red_kernel<<<64, 256, 0, stream>>>(part, g4, b4, A4, B4c, 64, N1);
    bnrelu_kernel<64><<<cdiv((ll)N1 * 8, 256), 256, 0, stream>>>(zb, A4, B4c, d2b, (ll)N1 * 8);

    // L5: upconv(64->32) + fused BN+ReLU+1x1
    mup_kernel<64, 32><<<cdiv(N0, 64), 256, 0, stream>>>(d2b, up0_idx, up0_off, W5t, zb, N0);
    statsp_kernel<32><<<256, 256, 0, stream>>>(zb, part, N0);
    red_kernel<<<32, 256, 0, stream>>>(part, g5, b5, A5, B5c, 32, N0);
    outk_kernel<<<cdiv(N0, 256), 256, 0, stream>>>(zb, A5, B5c, Wout, (float*)d_out, N0);
}

// Round 4
// 292.803 us; speedup vs baseline: 6.6306x; 1.7078x over previous
//
#include <hip/hip_runtime.h>
#include <hip/hip_bf16.h>

typedef __attribute__((ext_vector_type(4))) float  f32x4;
typedef __attribute__((ext_vector_type(8))) short  short8;
typedef __attribute__((ext_vector_type(2))) float  flt2;
typedef long long ll;

__device__ __forceinline__ short f2bf(float f) {
    __hip_bfloat16 h = __float2bfloat16(f);
    short s; __builtin_memcpy(&s, &h, 2);
    return s;
}
__device__ __forceinline__ float bf2f(short s) {
    unsigned u = ((unsigned)(unsigned short)s) << 16;
    float f; __builtin_memcpy(&f, &u, 4);
    return f;
}
__device__ __forceinline__ void gload_lds16(const void* g, void* l) {
    __builtin_amdgcn_global_load_lds(
        (const __attribute__((address_space(1))) unsigned*)(g),
        (__attribute__((address_space(3))) unsigned*)(l),
        16, 0, 0);
}

// ---------------------------------------------------------------------------
// prep: convert/transpose weights to bf16 [k][co][ci].
// W4t flattens to [512][128] (co512 = off*64+c), W5t to [256][64].
// ---------------------------------------------------------------------------
__global__ void prep_kernel(const float* __restrict__ W1, const float* __restrict__ W2,
                            const float* __restrict__ W3, const float* __restrict__ W4,
                            const float* __restrict__ W5,
                            short* W1t, short* W2t, short* W3t, short* W4t, short* W5t) {
    int gid = blockIdx.x * 256 + threadIdx.x;
    if (gid < 32 * 64) {                       // W1t[co][e], e=2k+ci, pad e>=54
        int co = gid >> 6, e = gid & 63;
        float v = 0.f;
        if (e < 54) { int k = e >> 1, ci = e & 1; v = W1[(k * 2 + ci) * 32 + co]; }
        W1t[gid] = f2bf(v);
        return;
    }
    int g = gid - 32 * 64;
    if (g < 27 * 64 * 32) { int k = g / (64*32), r = g % (64*32), co = r >> 5, ci = r & 31;
        W2t[g] = f2bf(W2[((ll)k * 32 + ci) * 64 + co]); return; }
    g -= 27 * 64 * 32;
    if (g < 27 * 128 * 64) { int k = g / (128*64), r = g % (128*64), co = r >> 6, ci = r & 63;
        W3t[g] = f2bf(W3[((ll)k * 64 + ci) * 128 + co]); return; }
    g -= 27 * 128 * 64;
    if (g < 8 * 64 * 128) { int k = g / (64*128), r = g % (64*128), co = r >> 7, ci = r & 127;
        W4t[g] = f2bf(W4[((ll)k * 128 + ci) * 64 + co]); return; }
    g -= 8 * 64 * 128;
    if (g < 8 * 32 * 64) { int k = g / (32*64), r = g % (32*64), co = r >> 6, ci = r & 63;
        W5t[g] = f2bf(W5[((ll)k * 64 + ci) * 32 + co]); return; }
}

// ---------------------------------------------------------------------------
// conv1 as dense MFMA GEMM: A[r][e] = feats[nbr[e/2][r]][e&1] (K=54 pad 64)
// ---------------------------------------------------------------------------
__launch_bounds__(256)
__global__ void c1_kernel(const float* __restrict__ feats, const int* __restrict__ nbr,
                          const short* __restrict__ W1t, short* __restrict__ out, int N) {
    int tid = threadIdx.x, lane = tid & 63, wave = tid >> 6;
    int rb = blockIdx.x * 64 + wave * 16;
    int r = rb + (lane & 15);
    int rl = r < N ? r : N - 1;
    int seg = lane >> 4;
    f32x4 acc[2];
    acc[0] = (f32x4){0,0,0,0}; acc[1] = (f32x4){0,0,0,0};
    short8 a[2];
    #pragma unroll
    for (int kc = 0; kc < 2; ++kc) {
        #pragma unroll
        for (int j = 0; j < 4; ++j) {
            int k = kc * 16 + seg * 4 + j;
            flt2 f = (flt2){0.f, 0.f};
            if (k < 27) {
                int idx = nbr[(ll)k * N + rl];
                if (idx >= 0) f = *(const flt2*)(feats + 2 * (ll)idx);
            }
            a[kc][2*j]   = f2bf(f[0]);
            a[kc][2*j+1] = f2bf(f[1]);
        }
    }
    #pragma unroll
    for (int kc = 0; kc < 2; ++kc)
        #pragma unroll
        for (int c = 0; c < 2; ++c) {
            short8 b = *(const short8*)(W1t + (c*16 + (lane & 15)) * 64 + kc * 32 + seg * 8);
            acc[c] = __builtin_amdgcn_mfma_f32_16x16x32_bf16(a[kc], b, acc[c], 0, 0, 0);
        }
    int r0 = rb + seg * 4;
    #pragma unroll
    for (int c = 0; c < 2; ++c) {
        int col = c * 16 + (lane & 15);
        #pragma unroll
        for (int j = 0; j < 4; ++j)
            if (r0 + j < N) out[(ll)(r0 + j) * 32 + col] = f2bf(acc[c][j]);
    }
}

// ---------------------------------------------------------------------------
// MFMA implicit-GEMM conv. Block: 128 rows x 64 cols (grid.y = COUTF/64).
// 4 waves x 32 rows. B tile per k staged in LDS ([kc][seg][co] bijective
// layout -> conflict-free stage AND read), double-buffered. A register-direct
// gather, 1-deep prefetch; idx 2-deep. DENSE: NK==1, A rows = output rows.
// ---------------------------------------------------------------------------
template<int CIN, int COUTF, int NK, bool DENSE>
__launch_bounds__(256)
__global__ void mconv_kernel(const short* __restrict__ inb, const int* __restrict__ nbr,
                             const short* __restrict__ Wt, short* __restrict__ out, int N) {
    constexpr int KC = CIN / 32;
    constexpr int BIT = (64 * CIN / 8) / 256;     // staging issues per thread
    constexpr int NBUF = (NK > 1) ? 2 : 1;
    __shared__ __align__(16) short lb[NBUF][64 * CIN];

    const int tid = threadIdx.x, lane = tid & 63;
    const int wave = tid >> 6, seg = lane >> 4, l15 = lane & 15;
    const int cb = blockIdx.y * 64;
    const int rbase = blockIdx.x * 128 + wave * 32;
    int rl0 = rbase + l15;      if (rl0 >= N) rl0 = N - 1;
    int rl1 = rbase + 16 + l15; if (rl1 >= N) rl1 = N - 1;

    const short* wsrc = Wt + (ll)cb * CIN;

    auto stage = [&](int k, int buf) {
        #pragma unroll
        for (int it = 0; it < BIT; ++it) {
            int p = it * 256 + tid;
            int co = p & 63, sg = (p >> 6) & 3, kc = p >> 8;
            gload_lds16(wsrc + ((ll)k * COUTF + co) * CIN + kc * 32 + sg * 8,
                        &lb[buf][p * 8]);
        }
    };

    f32x4 acc[2][4];
    #pragma unroll
    for (int rg = 0; rg < 2; ++rg)
        #pragma unroll
        for (int c = 0; c < 4; ++c) acc[rg][c] = (f32x4){0.f, 0.f, 0.f, 0.f};

    short8 aC[2][KC], aN[2][KC];

    auto ldA = [&](short8 (&a)[2][KC], int i0, int i1) {
        const short* b0 = inb + (ll)(i0 < 0 ? 0 : i0) * CIN;
        const short* b1 = inb + (ll)(i1 < 0 ? 0 : i1) * CIN;
        #pragma unroll
        for (int kc = 0; kc < KC; ++kc) {
            short8 v0 = *(const short8*)(b0 + kc * 32 + seg * 8);
            short8 v1 = *(const short8*)(b1 + kc * 32 + seg * 8);
            if (i0 < 0) v0 = (short8){0,0,0,0,0,0,0,0};
            if (i1 < 0) v1 = (short8){0,0,0,0,0,0,0,0};
            a[0][kc] = v0; a[1][kc] = v1;
        }
    };

    auto compute = [&](int buf, short8 (&a)[2][KC]) {
        #pragma unroll
        for (int kc = 0; kc < KC; ++kc)
            #pragma unroll
            for (int c = 0; c < 4; ++c) {
                short8 b = *(const short8*)&lb[buf][((kc * 4 + seg) * 64 + c * 16 + l15) * 8];
                acc[0][c] = __builtin_amdgcn_mfma_f32_16x16x32_bf16(a[0][kc], b, acc[0][c], 0, 0, 0);
                acc[1][c] = __builtin_amdgcn_mfma_f32_16x16x32_bf16(a[1][kc], b, acc[1][c], 0, 0, 0);
            }
    };

    if constexpr (DENSE) {
        stage(0, 0);
        ldA(aC, rl0, rl1);
        __syncthreads();
        compute(0, aC);
    } else {
        stage(0, 0);
        ldA(aC, nbr[rl0], nbr[rl1]);
        int j0 = nbr[(ll)N + rl0], j1 = nbr[(ll)N + rl1];
        __syncthreads();
        for (int k = 0; k < NK; ++k) {
            int n0 = -1, n1 = -1;
            if (k + 1 < NK) {
                stage(k + 1, (k + 1) & 1);
                ldA(aN, j0, j1);
                if (k + 2 < NK) {
                    n0 = nbr[(ll)(k + 2) * N + rl0];
                    n1 = nbr[(ll)(k + 2) * N + rl1];
                }
            }
            compute(k & 1, aC);
            __syncthreads();
            #pragma unroll
            for (int kc = 0; kc < KC; ++kc) { aC[0][kc] = aN[0][kc]; aC[1][kc] = aN[1][kc]; }
            j0 = n0; j1 = n1;
        }
    }

    #pragma unroll
    for (int rg = 0; rg < 2; ++rg) {
        int rr = rbase + rg * 16 + seg * 4;
        #pragma unroll
        for (int c = 0; c < 4; ++c) {
            int col = cb + c * 16 + l15;
            #pragma unroll
            for (int j = 0; j < 4; ++j)
                if (rr + j < N) out[(ll)(rr + j) * COUTF + col] = f2bf(acc[rg][c][j]);
        }
    }
}

// ---------------------------------------------------------------------------
// BN stats: block partials (deterministic). GATH: read G[pidx[r], poff[r]].
// ---------------------------------------------------------------------------
template<int C, bool GATH>
__global__ void statsp_kernel(const short* __restrict__ x, const int* __restrict__ pidx,
                              const int* __restrict__ poff, float* __restrict__ part, int N) {
    constexpr int LPR = C / 8;
    constexpr int RPB = 256 / LPR;
    int cl = threadIdx.x % LPR, r0 = threadIdx.x / LPR;
    float s[8] = {0,0,0,0,0,0,0,0}, q[8] = {0,0,0,0,0,0,0,0};
    for (ll row = (ll)blockIdx.x * RPB + r0; row < N; row += (ll)gridDim.x * RPB) {
        const short* rp;
        if constexpr (GATH) rp = x + (ll)pidx[row] * (C * 8) + poff[row] * C;
        else                rp = x + row * C;
        short8 v = *(const short8*)(rp + cl * 8);
        #pragma unroll
        for (int j = 0; j < 8; ++j) { float f = bf2f(v[j]); s[j] += f; q[j] += f * f; }
    }
    __shared__ float ls[256][8], lq[256][8];
    #pragma unroll
    for (int j = 0; j < 8; ++j) { ls[threadIdx.x][j] = s[j]; lq[threadIdx.x][j] = q[j]; }
    __syncthreads();
    for (int str = 128; str >= LPR; str >>= 1) {
        if (threadIdx.x < str) {
            #pragma unroll
            for (int j = 0; j < 8; ++j) {
                ls[threadIdx.x][j] += ls[threadIdx.x + str][j];
                lq[threadIdx.x][j] += lq[threadIdx.x + str][j];
            }
        }
        __syncthreads();
    }
    if (threadIdx.x < LPR) {
        #pragma unroll
        for (int j = 0; j < 8; ++j) {
            part[(ll)blockIdx.x * 2 * C + threadIdx.x * 8 + j]     = ls[threadIdx.x][j];
            part[(ll)blockIdx.x * 2 * C + C + threadIdx.x * 8 + j] = lq[threadIdx.x][j];
        }
    }
}

// reduce partials -> per-channel scale A, shift B.  grid = C blocks.
__global__ void red_kernel(const float* __restrict__ part, const float* __restrict__ g,
                           const float* __restrict__ bb, float* __restrict__ A,
                           float* __restrict__ B, int C, int N) {
    int c = blockIdx.x;
    __shared__ float ls[256], lq[256];
    ls[threadIdx.x] = part[(ll)threadIdx.x * 2 * C + c];
    lq[threadIdx.x] = part[(ll)threadIdx.x * 2 * C + C + c];
    __syncthreads();
    for (int str = 128; str >= 1; str >>= 1) {
        if (threadIdx.x < str) {
            ls[threadIdx.x] += ls[threadIdx.x + str];
            lq[threadIdx.x] += lq[threadIdx.x + str];
        }
        __syncthreads();
    }
    if (threadIdx.x == 0) {
        float inv = 1.0f / (float)N;
        float mu = ls[0] * inv, var = lq[0] * inv - mu * mu;
        float a = g[c] * rsqrtf(var + 1e-5f);
        A[c] = a; B[c] = bb[c] - mu * a;
    }
}

// ---------------------------------------------------------------------------
// BN + ReLU -> bf16. GATH: source row gathered from G.
// ---------------------------------------------------------------------------
template<int C, bool GATH>
__global__ void bnrelu_kernel(const short* __restrict__ x, const int* __restrict__ pidx,
                              const int* __restrict__ poff, const float* __restrict__ A,
                              const float* __restrict__ B, short* __restrict__ out, int N) {
    constexpr int CPR = C / 8;
    int i = blockIdx.x * 256 + threadIdx.x;
    if (i >= N * CPR) return;
    int r = i / CPR, ch = i - r * CPR;
    const short* rp;
    if constexpr (GATH) rp = x + (ll)pidx[r] * (C * 8) + poff[r] * C + ch * 8;
    else                rp = x + (ll)r * C + ch * 8;
    short8 v = *(const short8*)rp;
    short8 o;
    #pragma unroll
    for (int j = 0; j < 8; ++j) {
        int c = ch * 8 + j;
        float y = fmaf(bf2f(v[j]), A[c], B[c]);
        o[j] = f2bf(y > 0.f ? y : 0.f);
    }
    *(short8*)(out + (ll)r * C + ch * 8) = o;
}

// fused gather + BN + ReLU + 1x1 out conv: thread per row
__global__ void outk_kernel(const short* __restrict__ G2, const int* __restrict__ pidx,
                            const int* __restrict__ poff, const float* __restrict__ A,
                            const float* __restrict__ B, const float* __restrict__ Wout,
                            float* __restrict__ out, int N) {
    __shared__ float w[64], sa[32], sb[32];
    if (threadIdx.x < 64) w[threadIdx.x] = Wout[threadIdx.x];
    if (threadIdx.x < 32) { sa[threadIdx.x] = A[threadIdx.x]; sb[threadIdx.x] = B[threadIdx.x]; }
    __syncthreads();
    int r = blockIdx.x * 256 + threadIdx.x;
    if (r >= N) return;
    const short* zp = G2 + (ll)pidx[r] * 256 + poff[r] * 32;
    float o0 = 0.f, o1 = 0.f;
    #pragma unroll
    for (int s4 = 0; s4 < 4; ++s4) {
        short8 v = *(const short8*)(zp + s4 * 8);
        #pragma unroll
        for (int j = 0; j < 8; ++j) {
            int c = s4 * 8 + j;
            float y = fmaf(bf2f(v[j]), sa[c], sb[c]);
            y = y > 0.f ? y : 0.f;
            o0 = fmaf(y, w[2*c], o0);
            o1 = fmaf(y, w[2*c+1], o1);
        }
    }
    out[(ll)r * 2]     = o0;
    out[(ll)r * 2 + 1] = o1;
}

extern "C" void kernel_launch(void* const* d_in, const int* in_sizes, int n_in,
                              void* d_out, int out_size, void* d_ws, size_t ws_size,
                              hipStream_t stream) {
    const float* feats = (const float*)d_in[0];
    const float* W1 = (const float*)d_in[1];
    const float* W2 = (const float*)d_in[2];
    const float* W3 = (const float*)d_in[3];
    const float* W4 = (const float*)d_in[4];
    const float* W5 = (const float*)d_in[5];
    const float* Wout = (const float*)d_in[6];
    const float* g1 = (const float*)d_in[7],  *b1 = (const float*)d_in[8];
    const float* g2 = (const float*)d_in[9],  *b2 = (const float*)d_in[10];
    const float* g3 = (const float*)d_in[11], *b3 = (const float*)d_in[12];
    const float* g4 = (const float*)d_in[13], *b4 = (const float*)d_in[14];
    const float* g5 = (const float*)d_in[15], *b5 = (const float*)d_in[16];
    const int* nbr0 = (const int*)d_in[17];
    const int* nbr1 = (const int*)d_in[18];
    const int* nbr2 = (const int*)d_in[19];
    const int* up1_idx = (const int*)d_in[20];
    const int* up1_off = (const int*)d_in[21];
    const int* up0_idx = (const int*)d_in[22];
    const int* up0_off = (const int*)d_in[23];

    const int N0 = in_sizes[0] / 2;
    const int N1 = in_sizes[20];
    const int N2 = in_sizes[19] / 27;

    char* cur = (char*)d_ws;
    auto alloc = [&](size_t bytes) { char* p = cur; cur += (bytes + 255) & ~255ULL; return p; };

    float* stats = (float*)alloc(640 * 4);
    float* A1 = stats,       *B1c = stats + 32;
    float* A2 = stats + 64,  *B2c = stats + 128;
    float* A3 = stats + 192, *B3c = stats + 320;
    float* A4 = stats + 448, *B4c = stats + 512;
    float* A5 = stats + 576, *B5c = stats + 608;
    float* part = (float*)alloc(256 * 256 * 4);

    size_t zmax = (size_t)N1 * 64;
    if ((size_t)N0 * 32  > zmax) zmax = (size_t)N0 * 32;
    if ((size_t)N2 * 128 > zmax) zmax = (size_t)N2 * 128;
    size_t gmax = (size_t)N2 * 512;
    if ((size_t)N1 * 256 > gmax) gmax = (size_t)N1 * 256;

    short* zb  = (short*)alloc(zmax * 2);             // raw conv out (bf16, reused)
    short* Gb  = (short*)alloc(gmax * 2);             // dense decoder GEMM out
    short* e1b = (short*)alloc((size_t)N0 * 32 * 2);
    short* e2b = (short*)alloc((size_t)N1 * 64 * 2);
    short* e3b = (short*)alloc((size_t)N2 * 128 * 2);
    short* d2b = (short*)alloc((size_t)N1 * 64 * 2);
    short* W1t = (short*)alloc(32 * 64 * 2);
    short* W2t = (short*)alloc((size_t)27 * 64 * 32 * 2);
    short* W3t = (short*)alloc((size_t)27 * 128 * 64 * 2);
    short* W4t = (short*)alloc((size_t)8 * 64 * 128 * 2);
    short* W5t = (short*)alloc((size_t)8 * 32 * 64 * 2);

    auto cdiv = [](ll a, ll b) { return (int)((a + b - 1) / b); };

    prep_kernel<<<cdiv(2048 + 55296 + 221184 + 65536 + 16384, 256), 256, 0, stream>>>(
        W1, W2, W3, W4, W5, W1t, W2t, W3t, W4t, W5t);

    // L1: conv(2->32)
    c1_kernel<<<cdiv(N0, 64), 256, 0, stream>>>(feats, nbr0, W1t, zb, N0);
    statsp_kernel<32, false><<<256, 256, 0, stream>>>(zb, nullptr, nullptr, part, N0);
    red_kernel<<<32, 256, 0, stream>>>(part, g1, b1, A1, B1c, 32, N0);
    bnrelu_kernel<32, false><<<cdiv((ll)N0 * 4, 256), 256, 0, stream>>>(zb, nullptr, nullptr, A1, B1c, e1b, N0);

    // L2: conv(32->64)
    mconv_kernel<32, 64, 27, false><<<dim3(cdiv(N1, 128), 1), 256, 0, stream>>>(e1b, nbr1, W2t, zb, N1);
    statsp_kernel<64, false><<<256, 256, 0, stream>>>(zb, nullptr, nullptr, part, N1);
    red_kernel<<<64, 256, 0, stream>>>(part, g2, b2, A2, B2c, 64, N1);
    bnrelu_kernel<64, false><<<cdiv((ll)N1 * 8, 256), 256, 0, stream>>>(zb, nullptr, nullptr, A2, B2c, e2b, N1);

    // L3: conv(64->128)
    mconv_kernel<64, 128, 27, false><<<dim3(cdiv(N2, 128), 2), 256, 0, stream>>>(e2b, nbr2, W3t, zb, N2);
    statsp_kernel<128, false><<<256, 256, 0, stream>>>(zb, nullptr, nullptr, part, N2);
    red_kernel<<<128, 256, 0, stream>>>(part, g3, b3, A3, B3c, 128, N2);
    bnrelu_kernel<128, false><<<cdiv((ll)N2 * 16, 256), 256, 0, stream>>>(zb, nullptr, nullptr, A3, B3c, e3b, N2);

    // L4: dense decoder GEMM G = e3 @ W4all  [N2, 512], then gathered BN
    mconv_kernel<128, 512, 1, true><<<dim3(cdiv(N2, 128), 8), 256, 0, stream>>>(e3b, nullptr, W4t, Gb, N2);
    statsp_kernel<64, true><<<256, 256, 0, stream>>>(Gb, up1_idx, up1_off, part, N1);
    red_kernel<<<64, 256, 0, stream>>>(part, g4, b4, A4, B4c, 64, N1);
    bnrelu_kernel<64, true><<<cdiv((ll)N1 * 8, 256), 256, 0, stream>>>(Gb, up1_idx, up1_off, A4, B4c, d2b, N1);

    // L5: dense decoder GEMM G2 = d2 @ W5all [N1, 256], gathered BN + 1x1 out
    mconv_kernel<64, 256, 1, true><<<dim3(cdiv(N1, 128), 4), 256, 0, stream>>>(d2b, nullptr, W5t, Gb, N1);
    statsp_kernel<32, true><<<256, 256, 0, stream>>>(Gb, up0_idx, up0_off, part, N0);
    red_kernel<<<32, 256, 0, stream>>>(part, g5, b5, A5, B5c, 32, N0);
    outk_kernel<<<cdiv(N0, 256), 256, 0, stream>>>(Gb, up0_idx, up0_off, A5, B5c, Wout, (float*)d_out, N0);
}